// Round 3
// baseline (804.933 us; speedup 1.0000x reference)
//
#include <hip/hip_runtime.h>

#define NN 768
#define CIN 128
#define COUT 64
#define CDG 39
#define CAA 22
#define CESM 1280

typedef __attribute__((ext_vector_type(8))) short short8;
typedef __attribute__((ext_vector_type(4))) float f32x4;

__device__ __forceinline__ unsigned short f2bf(float f) {
  union { float f; unsigned int i; } c; c.f = f;
  unsigned int u = c.i;
  u += 0x7fffu + ((u >> 16) & 1u);
  return (unsigned short)(u >> 16);
}
__device__ __forceinline__ unsigned int pk(float a, float b) {
  return (unsigned int)f2bf(a) | ((unsigned int)f2bf(b) << 16);
}

struct Args {
  const float *td, *aa, *q, *pbm, *bbm, *mc, *ux, *uy, *uz, *esm;
  const float *w_dgram, *b_dgram, *w_aa1, *b_aa1, *w_aa2, *b_aa2;
  const float *ln_g, *ln_b, *w_q, *b_q;
  const float *w_pbm, *b_pbm, *w_x, *b_x, *w_y, *b_y, *w_z, *b_z, *w_bb, *b_bb;
  const float *w_esm1, *b_esm1, *w_esm2, *b_esm2;
  float* out;
  float* row_vec; float* col_vec; unsigned short* b_pack;
};

// ---------------------------------------------------------------------------
// Kernel 1: per-residue row/col vectors (aa + esm projections + all biases)
// and the packed B matrix (192 x 64) bf16 in 16x16x32 MFMA B-fragment order.
// B row k: [0,128)=w_q, [128,167)=w_dgram, 167=w_pbm, 168..170=w_x/y/z,
// 171=w_bb, [172,192)=zero.
// ---------------------------------------------------------------------------
__global__ __launch_bounds__(256) void k_pre(Args a) {
  const int b = blockIdx.x;
  const int tid = threadIdx.x;
  if (b == NN) {
    // B_pack element e = ((q*4+t)*64 + lane)*8 + j  holds  B[k][n] as bf16
    for (int e = tid; e < 12288; e += 256) {
      int jj = e & 7;
      int lane = (e >> 3) & 63;
      int qt = e >> 9;
      int q = qt >> 2, t = qt & 3;
      int k = q * 32 + ((lane >> 4) << 3) + jj;
      int n = t * 16 + (lane & 15);
      float v = 0.f;
      if (k < CIN) v = a.w_q[k * COUT + n];
      else if (k < CIN + CDG) v = a.w_dgram[(k - CIN) * COUT + n];
      else if (k == 167) v = a.w_pbm[n];
      else if (k == 168) v = a.w_x[n];
      else if (k == 169) v = a.w_y[n];
      else if (k == 170) v = a.w_z[n];
      else if (k == 171) v = a.w_bb[n];
      a.b_pack[e] = f2bf(v);
    }
    return;
  }
  const int wv = tid >> 6, lane = tid & 63;
  float acc1 = 0.f, acc2 = 0.f;
  const int KT = CAA + CESM;           // 1302
  const int SL = (KT + 3) / 4;         // 326
  int k0 = wv * SL;
  int k1 = k0 + SL; if (k1 > KT) k1 = KT;
  for (int k = k0; k < k1; ++k) {
    float v; const float *w1, *w2;
    if (k < CAA) { v = a.aa[b * CAA + k]; w1 = a.w_aa1 + k * COUT; w2 = a.w_aa2 + k * COUT; }
    else { int e = k - CAA; v = a.esm[b * CESM + e]; w1 = a.w_esm1 + e * COUT; w2 = a.w_esm2 + e * COUT; }
    acc1 += v * w1[lane];
    acc2 += v * w2[lane];
  }
  __shared__ float red1[4][64];
  __shared__ float red2[4][64];
  red1[wv][lane] = acc1; red2[wv][lane] = acc2;
  __syncthreads();
  if (wv == 0) {
    float r1 = red1[0][lane] + red1[1][lane] + red1[2][lane] + red1[3][lane];
    float r2 = red2[0][lane] + red2[1][lane] + red2[2][lane] + red2[3][lane];
    float br = a.b_aa1[lane] + a.b_esm1[lane] + a.b_dgram[lane] +
               a.b_pbm[lane] + a.b_x[lane] + a.b_y[lane] +
               a.b_z[lane] + a.b_bb[lane] + a.b_q[lane];
    float bc = a.b_aa2[lane] + a.b_esm2[lane];
    a.row_vec[b * COUT + lane] = r1 + br;
    a.col_vec[b * COUT + lane] = r2 + bc;
  }
}

// ---------------------------------------------------------------------------
// Kernel 2: main fused kernel. One block = 64 pairs (fixed i, 64 j) x 64 out.
// A tile (64 x 192 bf16, stride 200): [0,128)=LN(q), [128,167)=td*bb2,
// 167=pb2, 168..170=unit*bb2, 171=bb2, [172,192)=0.
// 4 waves x (16 pairs x 64 channels) via mfma_f32_16x16x32_bf16.
// Output: float32.
// ---------------------------------------------------------------------------
__global__ __launch_bounds__(256, 3) void k_main(Args a) {
  const int jt = blockIdx.x;           // 0..11
  const int i  = blockIdx.y;           // 0..767
  const int jbase = jt * 64;
  const int tid = threadIdx.x;
  const int wv = tid >> 6, lane = tid & 63;

  __shared__ unsigned short A_lds[64][200];   // 25600 B
  __shared__ unsigned short B_lds[12288];     // 24576 B
  __shared__ float bb2_s[64];
  __shared__ float pb2_s[64];

  // pair masks
  if (tid < 64) {
    int j = jbase + tid;
    float mc  = a.mc[(size_t)i * NN + j];
    bb2_s[tid] = a.bbm[i] * a.bbm[j] * mc;
    pb2_s[tid] = a.pbm[i] * a.pbm[j] * mc;
  }

  // stage B_pack (ws -> LDS), 1536 int4
  {
    const int4* src = (const int4*)a.b_pack;
    int4* dst = (int4*)B_lds;
#pragma unroll
    for (int r = 0; r < 6; ++r) dst[tid + 256 * r] = src[tid + 256 * r];
  }

  // LayerNorm(q) staging: thread = (pair p, quarter s), 32 channels each
  {
    const int p = tid >> 2, s = tid & 3;
    const float* qrow = a.q + ((size_t)i * NN + jbase + p) * CIN + s * 32;
    float q32[32];
    const float4* qv = (const float4*)qrow;
#pragma unroll
    for (int blk = 0; blk < 8; ++blk) {
      float4 t4 = qv[blk];
      q32[blk * 4 + 0] = t4.x; q32[blk * 4 + 1] = t4.y;
      q32[blk * 4 + 2] = t4.z; q32[blk * 4 + 3] = t4.w;
    }
    float sum = 0.f, sq = 0.f;
#pragma unroll
    for (int c = 0; c < 32; ++c) { sum += q32[c]; sq += q32[c] * q32[c]; }
    // reduce across the 4 threads of this pair (adjacent lanes)
    sum += __shfl_xor(sum, 1); sum += __shfl_xor(sum, 2);
    sq  += __shfl_xor(sq, 1);  sq  += __shfl_xor(sq, 2);
    float mu  = sum * (1.f / 128.f);
    float var = sq * (1.f / 128.f) - mu * mu;
    float rs  = rsqrtf(var + 1e-5f);
    float gl[32], bl[32];
    const float4* gv = (const float4*)(a.ln_g + s * 32);
    const float4* hv = (const float4*)(a.ln_b + s * 32);
#pragma unroll
    for (int blk = 0; blk < 8; ++blk) {
      float4 g4 = gv[blk], h4 = hv[blk];
      gl[blk * 4 + 0] = g4.x; gl[blk * 4 + 1] = g4.y;
      gl[blk * 4 + 2] = g4.z; gl[blk * 4 + 3] = g4.w;
      bl[blk * 4 + 0] = h4.x; bl[blk * 4 + 1] = h4.y;
      bl[blk * 4 + 2] = h4.z; bl[blk * 4 + 3] = h4.w;
    }
    int4* dA = (int4*)&A_lds[p][s * 32];
#pragma unroll
    for (int blk = 0; blk < 4; ++blk) {
      union { int4 v; unsigned int w[4]; } o;
#pragma unroll
      for (int w2 = 0; w2 < 4; ++w2) {
        int c = blk * 8 + w2 * 2;
        o.w[w2] = pk((q32[c] - mu) * rs * gl[c] + bl[c],
                     (q32[c + 1] - mu) * rs * gl[c + 1] + bl[c + 1]);
      }
      dA[blk] = o.v;
    }
  }
  __syncthreads();   // bb2_s/pb2_s ready

  // dgram tile: contiguous 64*39 f32 span, flat-copied coalesced as float2
  {
    const float* base = a.td + ((size_t)i * NN + jbase) * CDG;
    const float2* src = (const float2*)base;   // 1248 float2
    for (int w = tid; w < (64 * CDG) / 2; w += 256) {
      float2 d2 = src[w];
      int f0 = w * 2;
      int p0 = (f0 * 26887) >> 20; int d0 = f0 - p0 * CDG;
      int f1 = f0 + 1;
      int p1 = (f1 * 26887) >> 20; int d1 = f1 - p1 * CDG;
      A_lds[p0][CIN + d0] = f2bf(d2.x * bb2_s[p0]);
      A_lds[p1][CIN + d1] = f2bf(d2.y * bb2_s[p1]);
    }
  }
  // rank-1 columns + zero pad
  if (tid < 64) {
    int p = tid;
    size_t gij = (size_t)i * NN + jbase + p;
    float bb = bb2_s[p];
    A_lds[p][167] = f2bf(pb2_s[p]);
    A_lds[p][168] = f2bf(a.ux[gij] * bb);
    A_lds[p][169] = f2bf(a.uy[gij] * bb);
    A_lds[p][170] = f2bf(a.uz[gij] * bb);
    A_lds[p][171] = f2bf(bb);
    unsigned int* zp = (unsigned int*)&A_lds[p][172];   // byte 344, 4-aligned
#pragma unroll
    for (int z = 0; z < 10; ++z) zp[z] = 0;             // cols 172..191
  }
  __syncthreads();

  // MFMA: wave wv -> pairs [wv*16, wv*16+16), all 64 channels (4 N-tiles)
  f32x4 acc[4];
#pragma unroll
  for (int t = 0; t < 4; ++t) { f32x4 z = {0.f, 0.f, 0.f, 0.f}; acc[t] = z; }
  const int m = lane & 15, quad = lane >> 4;
  const unsigned short* Ab = &A_lds[wv * 16 + m][quad * 8];
  const unsigned short* Bb = &B_lds[lane * 8];
#pragma unroll
  for (int q = 0; q < 6; ++q) {
    short8 af = *(const short8*)(Ab + q * 32);
#pragma unroll
    for (int t = 0; t < 4; ++t) {
      short8 bfr = *(const short8*)(Bb + (q * 4 + t) * 512);
      acc[t] = __builtin_amdgcn_mfma_f32_16x16x32_bf16(af, bfr, acc[t], 0, 0, 0);
    }
  }

  // epilogue: + row_vec[j] + col_vec[i], store float32
  const float* cvp = a.col_vec + (size_t)i * COUT;
#pragma unroll
  for (int t = 0; t < 4; ++t) {
    int n = t * 16 + m;
    float cv = cvp[n];
#pragma unroll
    for (int r = 0; r < 4; ++r) {
      int p = wv * 16 + quad * 4 + r;
      int j = jbase + p;
      float val = acc[t][r] + a.row_vec[j * COUT + n] + cv;
      a.out[((size_t)i * NN + j) * COUT + n] = val;
    }
  }
}

extern "C" void kernel_launch(void* const* d_in, const int* in_sizes, int n_in,
                              void* d_out, int out_size, void* d_ws, size_t ws_size,
                              hipStream_t stream) {
  Args a;
  a.td     = (const float*)d_in[0];
  a.aa     = (const float*)d_in[1];
  a.q      = (const float*)d_in[2];
  a.pbm    = (const float*)d_in[3];
  a.bbm    = (const float*)d_in[4];
  a.mc     = (const float*)d_in[5];
  a.ux     = (const float*)d_in[6];
  a.uy     = (const float*)d_in[7];
  a.uz     = (const float*)d_in[8];
  a.esm    = (const float*)d_in[9];
  a.w_dgram = (const float*)d_in[10]; a.b_dgram = (const float*)d_in[11];
  a.w_aa1   = (const float*)d_in[12]; a.b_aa1   = (const float*)d_in[13];
  a.w_aa2   = (const float*)d_in[14]; a.b_aa2   = (const float*)d_in[15];
  a.ln_g    = (const float*)d_in[16]; a.ln_b    = (const float*)d_in[17];
  a.w_q     = (const float*)d_in[18]; a.b_q     = (const float*)d_in[19];
  a.w_pbm   = (const float*)d_in[20]; a.b_pbm   = (const float*)d_in[21];
  a.w_x     = (const float*)d_in[22]; a.b_x     = (const float*)d_in[23];
  a.w_y     = (const float*)d_in[24]; a.b_y     = (const float*)d_in[25];
  a.w_z     = (const float*)d_in[26]; a.b_z     = (const float*)d_in[27];
  a.w_bb    = (const float*)d_in[28]; a.b_bb    = (const float*)d_in[29];
  a.w_esm1  = (const float*)d_in[30]; a.b_esm1  = (const float*)d_in[31];
  a.w_esm2  = (const float*)d_in[32]; a.b_esm2  = (const float*)d_in[33];
  a.out = (float*)d_out;
  a.row_vec = (float*)d_ws;                       // 768*64 f32
  a.col_vec = a.row_vec + NN * COUT;              // 768*64 f32
  a.b_pack  = (unsigned short*)(a.col_vec + NN * COUT);  // 12288 bf16

  hipLaunchKernelGGL(k_pre, dim3(NN + 1), dim3(256), 0, stream, a);
  hipLaunchKernelGGL(k_main, dim3(12, NN), dim3(256), 0, stream, a);
}